// Round 1
// baseline (321.678 us; speedup 1.0000x reference)
//
#include <hip/hip_runtime.h>

#define D 64
#define H 8
#define LSEQ 2048
#define KMAX 64
#define NCODES 256   // 2^H

// ---------------------------------------------------------------------------
// Kernel 1: per-position LSH code for the query tensor.
// code(b,l) = sum_h ( (sum_{d: x[d]>0} W[d][h]) > 0 ) << h
// ---------------------------------------------------------------------------
__global__ void qcode_kernel(const float* __restrict__ x,
                             const float* __restrict__ W,
                             int* __restrict__ code, int n) {
    __shared__ float Ws[D * H];
    for (int i = threadIdx.x; i < D * H; i += blockDim.x) Ws[i] = W[i];
    __syncthreads();

    int idx = blockIdx.x * blockDim.x + threadIdx.x;
    if (idx >= n) return;

    const float* xp = x + (size_t)idx * D;
    float s[H];
#pragma unroll
    for (int h = 0; h < H; ++h) s[h] = 0.0f;

    // Sequential over d to mirror the reference accumulation order.
    for (int d = 0; d < D; ++d) {
        float xv = xp[d];
        if (xv > 0.0f) {
#pragma unroll
            for (int h = 0; h < H; ++h) s[h] += Ws[d * H + h];  // same-d broadcast
        }
    }
    int c = 0;
#pragma unroll
    for (int h = 0; h < H; ++h) c |= (s[h] > 0.0f) ? (1 << h) : 0;
    code[idx] = c;
}

// ---------------------------------------------------------------------------
// Kernel 2: one block per batch. Compute all key codes into LDS, then thread c
// collects the first <=KMAX ascending key indices whose code == c.
// ---------------------------------------------------------------------------
__global__ void __launch_bounds__(256)
bucket_kernel(const float* __restrict__ key,
              const float* __restrict__ W,
              int* __restrict__ bucket,   // [B][NCODES][KMAX]
              int* __restrict__ cnt) {    // [B][NCODES]
    __shared__ float Ws[D * H];
    __shared__ int kcode[LSEQ];
    int b = blockIdx.x;

    for (int i = threadIdx.x; i < D * H; i += blockDim.x) Ws[i] = W[i];
    __syncthreads();

    for (int l = threadIdx.x; l < LSEQ; l += blockDim.x) {
        const float* xp = key + ((size_t)b * LSEQ + l) * D;
        float s[H];
#pragma unroll
        for (int h = 0; h < H; ++h) s[h] = 0.0f;
        for (int d = 0; d < D; ++d) {
            float xv = xp[d];
            if (xv > 0.0f) {
#pragma unroll
                for (int h = 0; h < H; ++h) s[h] += Ws[d * H + h];
            }
        }
        int c = 0;
#pragma unroll
        for (int h = 0; h < H; ++h) c |= (s[h] > 0.0f) ? (1 << h) : 0;
        kcode[l] = c;
    }
    __syncthreads();

    int c = threadIdx.x;  // 256 threads == 256 codes
    int count = 0;
    int* bkt = bucket + ((size_t)b * NCODES + c) * KMAX;
    for (int i = 0; i < LSEQ; ++i) {          // all lanes read kcode[i]: broadcast
        if (kcode[i] == c) {
            if (count < KMAX) bkt[count] = i;
            ++count;
            if (count >= KMAX) break;
        }
    }
    cnt[b * NCODES + c] = count;              // ws is poisoned 0xAA: init here
}

// ---------------------------------------------------------------------------
// Kernel 3: emit output rows. One thread per output element, coalesced.
// ---------------------------------------------------------------------------
__global__ void emit_kernel(const int* __restrict__ q_code,  // [B*LSEQ]
                            const int* __restrict__ bucket,
                            const int* __restrict__ cnt,
                            int* __restrict__ out, int total) {
    int t = blockIdx.x * blockDim.x + threadIdx.x;
    if (t >= total) return;
    int q = t >> 6;                 // KMAX = 64
    int j = t & (KMAX - 1);
    int b = q >> 11;                // LSEQ = 2048
    int c = q_code[q];
    int row = b * NCODES + c;
    int n = cnt[row];
    out[t] = (j < n) ? bucket[(size_t)row * KMAX + j] : -1;
}

extern "C" void kernel_launch(void* const* d_in, const int* in_sizes, int n_in,
                              void* d_out, int out_size, void* d_ws, size_t ws_size,
                              hipStream_t stream) {
    const float* query = (const float*)d_in[0];
    const float* key   = (const float*)d_in[1];
    const float* W     = (const float*)d_in[2];
    // d_in[3] = head_idx (unused)

    int n_pos = in_sizes[0] / D;        // B*L = 8192
    int B     = n_pos / LSEQ;           // 4

    // Workspace layout
    int* q_code = (int*)d_ws;                           // n_pos ints
    int* bucket = q_code + n_pos;                       // B*NCODES*KMAX ints
    int* cnt    = bucket + (size_t)B * NCODES * KMAX;   // B*NCODES ints

    {
        int threads = 256;
        int blocks = (n_pos + threads - 1) / threads;
        qcode_kernel<<<blocks, threads, 0, stream>>>(query, W, q_code, n_pos);
    }
    {
        bucket_kernel<<<B, 256, 0, stream>>>(key, W, bucket, cnt);
    }
    {
        int total = out_size;           // B*L*KMAX
        int threads = 256;
        int blocks = (total + threads - 1) / threads;
        emit_kernel<<<blocks, threads, 0, stream>>>(q_code, bucket, cnt,
                                                    (int*)d_out, total);
    }
}

// Round 2
// 81.365 us; speedup vs baseline: 3.9535x; 3.9535x over previous
//
#include <hip/hip_runtime.h>

#define D 64
#define H 8
#define LSEQ 2048
#define KMAX 64
#define NCODES 256   // 2^H

// ---------------------------------------------------------------------------
// Kernel 1: LSH codes for BOTH query and key positions.
// code = sum_h ( (sum_{d: x[d]>0} W[d][h]) > 0 ) << h
// Thread t < n_pos -> query position t; else key position t - n_pos.
// ---------------------------------------------------------------------------
__global__ void code_kernel(const float* __restrict__ query,
                            const float* __restrict__ key,
                            const float* __restrict__ W,
                            int* __restrict__ q_code,   // [n_pos]
                            int* __restrict__ k_code,   // [n_pos]
                            int n_pos) {
    __shared__ float Ws[D * H];
    for (int i = threadIdx.x; i < D * H; i += blockDim.x) Ws[i] = W[i];
    __syncthreads();

    int t = blockIdx.x * blockDim.x + threadIdx.x;
    if (t >= 2 * n_pos) return;

    const float* xp = (t < n_pos) ? (query + (size_t)t * D)
                                  : (key + (size_t)(t - n_pos) * D);
    float s[H];
#pragma unroll
    for (int h = 0; h < H; ++h) s[h] = 0.0f;

    // Sequential over d to mirror the reference accumulation order (absmax=0 in R0).
    for (int d4 = 0; d4 < D / 4; ++d4) {
        float4 xv = ((const float4*)xp)[d4];
        const float* x4 = (const float*)&xv;
#pragma unroll
        for (int k = 0; k < 4; ++k) {
            if (x4[k] > 0.0f) {
                int d = d4 * 4 + k;
#pragma unroll
                for (int h = 0; h < H; ++h) s[h] += Ws[d * H + h];
            }
        }
    }
    int c = 0;
#pragma unroll
    for (int h = 0; h < H; ++h) c |= (s[h] > 0.0f) ? (1 << h) : 0;

    if (t < n_pos) q_code[t] = c;
    else           k_code[t - n_pos] = c;
}

// ---------------------------------------------------------------------------
// Kernel 2: one WAVE per (batch, code). Wave-ballot stream compaction:
// sweep 2048 key codes in 32 chunks of 64, collect first <=KMAX ascending
// indices with code == c.
// ---------------------------------------------------------------------------
__global__ void __launch_bounds__(64)
bucket_ballot_kernel(const int* __restrict__ k_code,   // [B][LSEQ]
                     int* __restrict__ bucket,         // [B][NCODES][KMAX]
                     int* __restrict__ cnt) {          // [B][NCODES]
    int c = blockIdx.x & (NCODES - 1);
    int b = blockIdx.x >> 8;
    int lane = threadIdx.x;   // block = exactly one wave of 64

    const int* kc = k_code + (size_t)b * LSEQ;
    int* bkt = bucket + ((size_t)b * NCODES + c) * KMAX;

    unsigned long long lt_mask = (lane == 63) ? 0x7FFFFFFFFFFFFFFFull
                                              : ((1ull << lane) - 1ull);
    int base = 0;
#pragma unroll 4
    for (int i = 0; i < LSEQ / 64; ++i) {
        int idx = i * 64 + lane;
        int ci = kc[idx];                             // coalesced, L2-hot
        unsigned long long mask = __ballot(ci == c);  // 64-bit on wave64
        if (ci == c) {
            int rank = base + __popcll(mask & lt_mask);
            if (rank < KMAX) bkt[rank] = idx;
        }
        base += __popcll(mask);
        if (base >= KMAX) break;                      // wave-uniform
    }
    if (lane == 0) cnt[b * NCODES + c] = (base < KMAX) ? base : KMAX;
}

// ---------------------------------------------------------------------------
// Kernel 3: emit output rows. One thread per output element, coalesced.
// ---------------------------------------------------------------------------
__global__ void emit_kernel(const int* __restrict__ q_code,  // [B*LSEQ]
                            const int* __restrict__ bucket,
                            const int* __restrict__ cnt,
                            int* __restrict__ out, int total) {
    int t = blockIdx.x * blockDim.x + threadIdx.x;
    if (t >= total) return;
    int q = t >> 6;                 // KMAX = 64
    int j = t & (KMAX - 1);
    int b = q >> 11;                // LSEQ = 2048
    int c = q_code[q];
    int row = b * NCODES + c;
    int n = cnt[row];
    out[t] = (j < n) ? bucket[(size_t)row * KMAX + j] : -1;
}

extern "C" void kernel_launch(void* const* d_in, const int* in_sizes, int n_in,
                              void* d_out, int out_size, void* d_ws, size_t ws_size,
                              hipStream_t stream) {
    const float* query = (const float*)d_in[0];
    const float* key   = (const float*)d_in[1];
    const float* W     = (const float*)d_in[2];
    // d_in[3] = head_idx (unused)

    int n_pos = in_sizes[0] / D;        // B*L = 8192
    int B     = n_pos / LSEQ;           // 4

    // Workspace layout (ints)
    int* q_code = (int*)d_ws;                           // n_pos
    int* k_code = q_code + n_pos;                       // n_pos
    int* bucket = k_code + n_pos;                       // B*NCODES*KMAX
    int* cnt    = bucket + (size_t)B * NCODES * KMAX;   // B*NCODES

    {
        int threads = 256;
        int blocks = (2 * n_pos + threads - 1) / threads;
        code_kernel<<<blocks, threads, 0, stream>>>(query, key, W,
                                                    q_code, k_code, n_pos);
    }
    {
        bucket_ballot_kernel<<<B * NCODES, 64, 0, stream>>>(k_code, bucket, cnt);
    }
    {
        int total = out_size;           // B*L*KMAX
        int threads = 256;
        int blocks = (total + threads - 1) / threads;
        emit_kernel<<<blocks, threads, 0, stream>>>(q_code, bucket, cnt,
                                                    (int*)d_out, total);
    }
}